// Round 4
// baseline (167.016 us; speedup 1.0000x reference)
//
#include <hip/hip_runtime.h>

#define D 64
#define CPAD 16        // counts stride in ints: one counter per 64B line
#define GEMM_BLOCKS 1024
#define HIST_BLOCKS 2048

// Fused: blocks [0,GEMM_BLOCKS) compute y = x * W^T (W rows in registers);
//        blocks [GEMM_BLOCKS,..) do the dst histogram + per-edge rank.
__global__ void gemm_hist_kernel(const float* __restrict__ x, const float* __restrict__ W,
                                 float* __restrict__ y,
                                 const int* __restrict__ dst, int* __restrict__ counts,
                                 int* __restrict__ rank, int n_nodes, int ne) {
    if (blockIdx.x < GEMM_BLOCKS) {
        __shared__ float As[4][D];
        const int tid = threadIdx.x;
        const int w = tid >> 6, o = tid & 63;
        const float4* W4 = (const float4*)W;
        float4 wr[16];
#pragma unroll
        for (int k = 0; k < 16; ++k) wr[k] = W4[o * 16 + k];  // W row o (16 KB total, L2)
        const int ngrp = (n_nodes + 3) >> 2;
        for (int grp = blockIdx.x; grp < ngrp; grp += GEMM_BLOCKS) {
            const int base = grp * 4;
            __syncthreads();  // As consumed from previous iteration
            if (base * D + tid < n_nodes * D) As[tid >> 6][tid & 63] = x[base * D + tid];
            __syncthreads();
            const int n = base + w;
            if (n < n_nodes) {
                float h = 0.f;
#pragma unroll
                for (int k = 0; k < 16; ++k) {
                    const float4 a = *(const float4*)&As[w][k * 4];  // LDS broadcast
                    h = fmaf(a.x, wr[k].x, h);
                    h = fmaf(a.y, wr[k].y, h);
                    h = fmaf(a.z, wr[k].z, h);
                    h = fmaf(a.w, wr[k].w, h);
                }
                y[(size_t)n * D + o] = h;
            }
        }
    } else {
        const int stride = HIST_BLOCKS * 256;
        for (int e = (blockIdx.x - GEMM_BLOCKS) * 256 + threadIdx.x; e < ne; e += stride) {
            const int d = dst[e];
            rank[e] = atomicAdd(&counts[(size_t)d * CPAD], 1);
        }
    }
}

// Exclusive scan of padded counts, 256/block
__global__ void scan1_kernel(const int* __restrict__ counts, int* __restrict__ scanned,
                             int* __restrict__ bsums, int n) {
    __shared__ int s[256];
    const int t = threadIdx.x;
    const int i = blockIdx.x * 256 + t;
    const int v = (i < n) ? counts[(size_t)i * CPAD] : 0;
    s[t] = v;
    __syncthreads();
    for (int off = 1; off < 256; off <<= 1) {
        int u = (t >= off) ? s[t - off] : 0;
        __syncthreads();
        s[t] += u;
        __syncthreads();
    }
    if (i < n) scanned[i] = s[t] - v;  // exclusive within block
    if (t == 255) bsums[blockIdx.x] = s[255];
}

__global__ void scan2_kernel(const int* __restrict__ bsums, int* __restrict__ bscan, int nb) {
    __shared__ int s[256];
    const int t = threadIdx.x;
    const int v = (t < nb) ? bsums[t] : 0;
    s[t] = v;
    __syncthreads();
    for (int off = 1; off < 256; off <<= 1) {
        int u = (t >= off) ? s[t - off] : 0;
        __syncthreads();
        s[t] += u;
        __syncthreads();
    }
    if (t < nb) bscan[t] = s[t] - v;  // exclusive
}

// Atomic-free placement using precomputed ranks
__global__ void place_kernel(const int* __restrict__ src, const int* __restrict__ dst,
                             const int* __restrict__ scanned, const int* __restrict__ bscan,
                             const int* __restrict__ rank, int* __restrict__ esrc, int ne) {
    int e = blockIdx.x * blockDim.x + threadIdx.x;
    if (e < ne) {
        int d = dst[e];
        esrc[scanned[d] + bscan[d >> 8] + rank[e]] = src[e];
    }
}

// Gather-sum of y rows + relu + residual. One wave per node; 16 lanes x float4 per row,
// 8 edges in flight; no LDS, no barriers.
__global__ void gather_kernel(const int* __restrict__ scanned, const int* __restrict__ bscan,
                              const int* __restrict__ counts, const int* __restrict__ esrc,
                              const float* __restrict__ y, const float* __restrict__ x,
                              float* __restrict__ out, int n_nodes) {
    const int tid = threadIdx.x;
    const int w = tid >> 6, lane = tid & 63;
    const int g = lane >> 4, m = lane & 15;
    const float4* y4 = (const float4*)y;
    const float4* x4 = (const float4*)x;
    float4* out4 = (float4*)out;
    const int waveId = blockIdx.x * 4 + w;
    const int nWaves = gridDim.x * 4;

    for (int n = waveId; n < n_nodes; n += nWaves) {
        const int start = scanned[n] + bscan[n >> 8];
        const int c = counts[(size_t)n * CPAD];
        float4 acc = {0.f, 0.f, 0.f, 0.f};
        int j = 0;
        for (; j + 8 <= c; j += 8) {
            const int s0 = esrc[start + j + g];
            const int s1 = esrc[start + j + 4 + g];
            const float4 v0 = y4[(size_t)s0 * 16 + m];
            const float4 v1 = y4[(size_t)s1 * 16 + m];
            acc.x += v0.x; acc.y += v0.y; acc.z += v0.z; acc.w += v0.w;
            acc.x += v1.x; acc.y += v1.y; acc.z += v1.z; acc.w += v1.w;
        }
        if (j < c) {  // tail: 1..7 edges, clamped-safe loads + predicated adds
            const int e0 = j + g, e1 = j + 4 + g;
            const int i0 = start + (e0 < c ? e0 : c - 1);
            const int i1 = start + (e1 < c ? e1 : c - 1);
            const int s0 = esrc[i0], s1 = esrc[i1];
            const float4 v0 = y4[(size_t)s0 * 16 + m];
            const float4 v1 = y4[(size_t)s1 * 16 + m];
            if (e0 < c) { acc.x += v0.x; acc.y += v0.y; acc.z += v0.z; acc.w += v0.w; }
            if (e1 < c) { acc.x += v1.x; acc.y += v1.y; acc.z += v1.z; acc.w += v1.w; }
        }
        // reduce the 4 edge-slot groups (lanes differing in bits 4,5)
        acc.x += __shfl_xor(acc.x, 16); acc.y += __shfl_xor(acc.y, 16);
        acc.z += __shfl_xor(acc.z, 16); acc.w += __shfl_xor(acc.w, 16);
        acc.x += __shfl_xor(acc.x, 32); acc.y += __shfl_xor(acc.y, 32);
        acc.z += __shfl_xor(acc.z, 32); acc.w += __shfl_xor(acc.w, 32);
        if (lane < 16) {
            const float4 r = x4[(size_t)n * 16 + lane];
            float4 o4;
            o4.x = fmaxf(acc.x, 0.f) + r.x;
            o4.y = fmaxf(acc.y, 0.f) + r.y;
            o4.z = fmaxf(acc.z, 0.f) + r.z;
            o4.w = fmaxf(acc.w, 0.f) + r.w;
            out4[(size_t)n * 16 + lane] = o4;
        }
    }
}

extern "C" void kernel_launch(void* const* d_in, const int* in_sizes, int n_in,
                              void* d_out, int out_size, void* d_ws, size_t ws_size,
                              hipStream_t stream) {
    const float* x = (const float*)d_in[0];
    const float* W = (const float*)d_in[1];
    const int* src = (const int*)d_in[2];
    const int* dst = (const int*)d_in[3];
    float* out = (float*)d_out;

    const int n_nodes = in_sizes[0] / D;
    const int n_edges = in_sizes[2];

    // workspace layout: ~22.6 MB
    int* counts  = (int*)d_ws;                       // n_nodes * CPAD
    int* scanned = counts + (size_t)n_nodes * CPAD;  // n_nodes
    int* bsums   = scanned + n_nodes;                // 256
    int* bscan   = bsums + 256;                      // 256
    int* rank    = bscan + 256;                      // n_edges
    int* esrc    = rank + n_edges;                   // n_edges
    float* y     = (float*)(esrc + n_edges);         // n_nodes * D

    hipMemsetAsync(counts, 0, (size_t)n_nodes * CPAD * sizeof(int), stream);

    const int egrid = (n_edges + 255) / 256;
    const int ngrid = (n_nodes + 255) / 256;  // 196 <= 256: scan2 fits in one block

    gemm_hist_kernel<<<GEMM_BLOCKS + HIST_BLOCKS, 256, 0, stream>>>(
        x, W, y, dst, counts, rank, n_nodes, n_edges);
    scan1_kernel<<<ngrid, 256, 0, stream>>>(counts, scanned, bsums, n_nodes);
    scan2_kernel<<<1, 256, 0, stream>>>(bsums, bscan, ngrid);
    place_kernel<<<egrid, 256, 0, stream>>>(src, dst, scanned, bscan, rank, esrc, n_edges);

    gather_kernel<<<2048, 256, 0, stream>>>(scanned, bscan, counts, esrc, y, x, out, n_nodes);
}